// Round 2
// baseline (177.116 us; speedup 1.0000x reference)
//
#include <hip/hip_runtime.h>
#include <math.h>

#define N_B 2
#define HH 48
#define WW 48
#define DM 256
#define NH 4
#define EH 64
#define KS 7
#define NPIX (N_B*HH*WW)   // 4608
#define NQ   (N_B*NH*HH*WW) // 18432 attention queries

// ---------------- scale = cond @ w_norm.T + 1 ----------------
__global__ void scale_kernel(const float* __restrict__ cond,
                             const float* __restrict__ w_norm,
                             float* __restrict__ scale) {
    int b = blockIdx.x, d = threadIdx.x;
    __shared__ float csh[DM];
    csh[d] = cond[b*DM + d];
    __syncthreads();
    const float* wr = w_norm + (size_t)d*DM;
    float acc = 0.f;
    #pragma unroll 8
    for (int c = 0; c < DM; ++c) acc += csh[c]*wr[c];
    scale[b*DM + d] = acc + 1.0f;
}

// ---------------- RMSNorm: xn = x * scale * rsqrt(mean(x^2)+eps) ----------------
__global__ void rmsnorm_kernel(const float* __restrict__ x,
                               const float* __restrict__ scale,
                               float* __restrict__ xn) {
    int pix = blockIdx.x, t = threadIdx.x;
    int b = pix / (HH*WW);
    float v = x[(size_t)pix*DM + t];
    float ss = v*v;
    #pragma unroll
    for (int off = 32; off > 0; off >>= 1) ss += __shfl_xor(ss, off, 64);
    __shared__ float wsum[4];
    if ((t & 63) == 0) wsum[t>>6] = ss;
    __syncthreads();
    float tot = wsum[0]+wsum[1]+wsum[2]+wsum[3];
    float r = rsqrtf(tot*(1.0f/DM) + 1e-6f);
    xn[(size_t)pix*DM + t] = v * scale[b*DM + t] * r;
}

// ---------------- C[MxN] = A[MxK] * B[NxK]^T (+skip) ----------------
// 64x64 tile, 256 threads, 4x4 per thread, BK=16, k-major LDS (pad 4 keeps 16B align, 2-way bank alias = free)
__global__ __launch_bounds__(256) void gemm_nt(const float* __restrict__ A,
                                               const float* __restrict__ B,
                                               float* __restrict__ C,
                                               const float* __restrict__ skip,
                                               int M, int N, int K) {
    const int BM = 64, BN = 64, BK = 16;
    __shared__ float As[BK][BM+4];
    __shared__ float Bs[BK][BN+4];
    int t = threadIdx.x;
    int m0 = blockIdx.x*BM, n0 = blockIdx.y*BN;
    int ty = t >> 4, tx = t & 15;
    int lrow = t >> 2, lkg = t & 3;
    float acc[4][4] = {};
    for (int k0 = 0; k0 < K; k0 += BK) {
        float4 av = *(const float4*)(A + (size_t)(m0+lrow)*K + k0 + lkg*4);
        float4 bv = *(const float4*)(B + (size_t)(n0+lrow)*K + k0 + lkg*4);
        As[lkg*4+0][lrow]=av.x; As[lkg*4+1][lrow]=av.y; As[lkg*4+2][lrow]=av.z; As[lkg*4+3][lrow]=av.w;
        Bs[lkg*4+0][lrow]=bv.x; Bs[lkg*4+1][lrow]=bv.y; Bs[lkg*4+2][lrow]=bv.z; Bs[lkg*4+3][lrow]=bv.w;
        __syncthreads();
        #pragma unroll
        for (int kk = 0; kk < BK; ++kk) {
            float a[4], bb[4];
            *(float4*)a  = *(const float4*)&As[kk][ty*4];
            *(float4*)bb = *(const float4*)&Bs[kk][tx*4];
            #pragma unroll
            for (int i = 0; i < 4; ++i)
                #pragma unroll
                for (int j = 0; j < 4; ++j)
                    acc[i][j] = fmaf(a[i], bb[j], acc[i][j]);
        }
        __syncthreads();
    }
    #pragma unroll
    for (int i = 0; i < 4; ++i) {
        int r = m0 + ty*4 + i;
        #pragma unroll
        for (int j = 0; j < 4; ++j) {
            int c = n0 + tx*4 + j;
            float v = acc[i][j];
            if (skip) v += skip[(size_t)r*N + c];
            C[(size_t)r*N + c] = v;
        }
    }
}

// ---------------- RoPE on q (sel=0, with 1/8 scale) and k (sel=1) ----------------
// reads qkv[pix][sel*256 + head*64 + e], writes qr[pix][sel*256 + head*64 + e]
__global__ void rope_kernel(const float* __restrict__ pos,
                            const float* __restrict__ qkv,
                            float* __restrict__ qr) {
    int pix = blockIdx.x;
    int sel = blockIdx.y;   // 0=q, 1=k
    int t = threadIdx.x;    // 256: head = t/64, e = t%64
    int hw = pix % (HH*WW);
    const float* src = qkv + (size_t)pix*768 + sel*DM;
    float* dst = qr + (size_t)pix*512 + sel*DM;
    int e = t & 63;
    float v = src[t];
    float outv;
    if (e < 32) {
        int m = e & 15;
        int mf = m & 7;
        float p = (m < 8) ? pos[hw*2] : pos[hw*2 + 1];
        // freqs[mf] = exp(log(pi) + mf * ln(10)/8)
        float freq = expf(1.14472988585f + mf * 0.287823136624f);
        float ang = p * freq;
        float c = cosf(ang), s = sinf(ang);
        float partner = (e < 16) ? src[t+16] : src[t-16];
        outv = (e < 16) ? fmaf(v, c, -partner*s) : fmaf(v, c, partner*s);
    } else {
        outv = v;
    }
    if (sel == 0) outv *= 0.125f;   // q / sqrt(64)
    dst[t] = outv;
}

// ---------------- neighborhood attention: one wave per query ----------------
__global__ __launch_bounds__(256) void attn_kernel(const float* __restrict__ qr,
                                                   const float* __restrict__ qkv,
                                                   float* __restrict__ obuf) {
    int t = threadIdx.x;
    int wave = t >> 6, lane = t & 63;
    int qid = blockIdx.x * 4 + wave;        // ((b*NH+head)*H + h)*W + w
    int w = qid % WW; int tmp = qid / WW;
    int h = tmp % HH; tmp /= HH;
    int head = tmp % NH; int b = tmp / NH;
    int pix = (b*HH + h)*WW + w;

    __shared__ float q_sh[4][EH];
    __shared__ float a_sh[4][EH];

    q_sh[wave][lane] = qr[(size_t)pix*512 + head*EH + lane];
    __syncthreads();

    int sh = min(max(h-3, 0), HH-KS);
    int sw = min(max(w-3, 0), WW-KS);

    float dot = -3.0e38f;
    if (lane < 49) {
        int p = lane / 7, qq = lane % 7;
        const float* kp = qr + (size_t)((b*HH + sh+p)*WW + sw+qq)*512 + DM + head*EH;
        float acc = 0.f;
        #pragma unroll
        for (int e4 = 0; e4 < 16; ++e4) {
            float4 kv = *(const float4*)(kp + e4*4);
            acc = fmaf(q_sh[wave][e4*4+0], kv.x, acc);
            acc = fmaf(q_sh[wave][e4*4+1], kv.y, acc);
            acc = fmaf(q_sh[wave][e4*4+2], kv.z, acc);
            acc = fmaf(q_sh[wave][e4*4+3], kv.w, acc);
        }
        dot = acc;
    }
    // softmax over 49 within the wave
    float mx = dot;
    #pragma unroll
    for (int off = 32; off > 0; off >>= 1) mx = fmaxf(mx, __shfl_xor(mx, off, 64));
    float ex = (lane < 49) ? expf(dot - mx) : 0.f;
    float sm = ex;
    #pragma unroll
    for (int off = 32; off > 0; off >>= 1) sm += __shfl_xor(sm, off, 64);
    a_sh[wave][lane] = ex / sm;
    __syncthreads();

    float o = 0.f;
    #pragma unroll
    for (int j = 0; j < 49; ++j) {
        int p = j / 7, qq = j % 7;
        const float* vp = qkv + (size_t)((b*HH + sh+p)*WW + sw+qq)*768 + 2*DM + head*EH;
        o = fmaf(a_sh[wave][j], vp[lane], o);
    }
    obuf[(size_t)pix*DM + head*EH + lane] = o;  // (b,h,w,head,e) = (b,h,w,d)
}

extern "C" void kernel_launch(void* const* d_in, const int* in_sizes, int n_in,
                              void* d_out, int out_size, void* d_ws, size_t ws_size,
                              hipStream_t stream) {
    const float* x      = (const float*)d_in[0];
    const float* pos    = (const float*)d_in[1];
    const float* cond   = (const float*)d_in[2];
    const float* w_norm = (const float*)d_in[3];
    const float* w_qkv  = (const float*)d_in[4];
    const float* w_out  = (const float*)d_in[5];
    float* out = (float*)d_out;
    float* ws  = (float*)d_ws;

    // workspace layout (floats)
    float* scale = ws;                              // 512 (pad to 1024)
    float* xn    = ws + 1024;                       // NPIX*256
    float* qkv   = xn + (size_t)NPIX*DM;            // NPIX*768
    float* qr    = qkv + (size_t)NPIX*768;          // NPIX*512
    float* obuf  = qr + (size_t)NPIX*512;           // NPIX*256
    // total ~8.26M floats = 33 MB

    scale_kernel<<<dim3(N_B), dim3(DM), 0, stream>>>(cond, w_norm, scale);
    rmsnorm_kernel<<<dim3(NPIX), dim3(DM), 0, stream>>>(x, scale, xn);
    gemm_nt<<<dim3(NPIX/64, 768/64), 256, 0, stream>>>(xn, w_qkv, qkv, nullptr, NPIX, 768, DM);
    rope_kernel<<<dim3(NPIX, 2), dim3(DM), 0, stream>>>(pos, qkv, qr);
    attn_kernel<<<dim3(NQ/4), 256, 0, stream>>>(qr, qkv, obuf);   // R1 fix: NQ=18432 queries, was NPIX/4 (covered only 1/4)
    gemm_nt<<<dim3(NPIX/64, DM/64), 256, 0, stream>>>(obuf, w_out, out, x, NPIX, DM, DM);
}

// Round 3
// 173.469 us; speedup vs baseline: 1.0210x; 1.0210x over previous
//
#include <hip/hip_runtime.h>
#include <math.h>

#define N_B 2
#define HH 48
#define WW 48
#define DM 256
#define NH 4
#define EH 64
#define KS 7
#define NPIX (N_B*HH*WW)    // 4608
#define NQ   (N_B*NH*HH*WW) // 18432 attention queries

typedef _Float16 half8 __attribute__((ext_vector_type(8)));
typedef float float4v __attribute__((ext_vector_type(4)));

// ---------------- scale = cond @ w_norm.T + 1 ----------------
__global__ void scale_kernel(const float* __restrict__ cond,
                             const float* __restrict__ w_norm,
                             float* __restrict__ scale) {
    int b = blockIdx.x, d = threadIdx.x;
    __shared__ float csh[DM];
    csh[d] = cond[b*DM + d];
    __syncthreads();
    const float* wr = w_norm + (size_t)d*DM;
    float acc = 0.f;
    #pragma unroll 8
    for (int c = 0; c < DM; ++c) acc += csh[c]*wr[c];
    scale[b*DM + d] = acc + 1.0f;
}

// ---------------- RMSNorm -> fp16 output ----------------
__global__ void rmsnorm_kernel(const float* __restrict__ x,
                               const float* __restrict__ scale,
                               _Float16* __restrict__ xn) {
    int pix = blockIdx.x, t = threadIdx.x;
    int b = pix / (HH*WW);
    float v = x[(size_t)pix*DM + t];
    float ss = v*v;
    #pragma unroll
    for (int off = 32; off > 0; off >>= 1) ss += __shfl_xor(ss, off, 64);
    __shared__ float wsum[4];
    if ((t & 63) == 0) wsum[t>>6] = ss;
    __syncthreads();
    float tot = wsum[0]+wsum[1]+wsum[2]+wsum[3];
    float r = rsqrtf(tot*(1.0f/DM) + 1e-6f);
    xn[(size_t)pix*DM + t] = (_Float16)(v * scale[b*DM + t] * r);
}

// ---------------- fp32 -> fp16 cast ----------------
__global__ void cast_f16_kernel(const float* __restrict__ src, _Float16* __restrict__ dst, int n) {
    int i = blockIdx.x*256 + threadIdx.x;
    if (i < n) dst[i] = (_Float16)src[i];
}

// ---------------- C[MxN] = A[MxK] * B[NxK]^T (+skip), fp16 MFMA ----------------
// 128x64 block tile, 4 waves x (32x64), mfma 16x16x32, BK=32.
// LDS rows padded to 40 halves (80B): bank base advances 20 dwords/row -> <=2-way alias (free),
// 16B alignment preserved for ds_read_b128.
__global__ __launch_bounds__(256) void gemm_nt_f16(const _Float16* __restrict__ A,
                                                   const _Float16* __restrict__ B,
                                                   float* __restrict__ C,
                                                   const float* __restrict__ skip,
                                                   int M, int N, int K) {
    const int LDT = 40;
    __shared__ _Float16 As[128*LDT];
    __shared__ _Float16 Bs[64*LDT];
    int t = threadIdx.x;
    int wave = t >> 6, lane = t & 63;
    int m0 = blockIdx.x*128, n0 = blockIdx.y*64;

    int lr = t >> 2;          // staging row 0..63
    int lk = (t & 3) * 8;     // k offset in halves: 0,8,16,24

    float4v acc[2][4];
    #pragma unroll
    for (int mi = 0; mi < 2; ++mi)
        #pragma unroll
        for (int ni = 0; ni < 4; ++ni)
            acc[mi][ni] = (float4v){0.f,0.f,0.f,0.f};

    int frow = lane & 15;          // fragment row within 16
    int kq   = (lane >> 4) * 8;    // fragment k base

    for (int k0 = 0; k0 < K; k0 += 32) {
        half8 a0 = *(const half8*)(A + (size_t)(m0 + lr)*K      + k0 + lk);
        half8 a1 = *(const half8*)(A + (size_t)(m0 + 64 + lr)*K + k0 + lk);
        half8 b0 = *(const half8*)(B + (size_t)(n0 + lr)*K      + k0 + lk);
        __syncthreads();
        *(half8*)&As[lr*LDT + lk]      = a0;
        *(half8*)&As[(64+lr)*LDT + lk] = a1;
        *(half8*)&Bs[lr*LDT + lk]      = b0;
        __syncthreads();
        half8 af[2], bf[4];
        af[0] = *(const half8*)&As[(wave*32 + frow)*LDT + kq];
        af[1] = *(const half8*)&As[(wave*32 + 16 + frow)*LDT + kq];
        #pragma unroll
        for (int ni = 0; ni < 4; ++ni)
            bf[ni] = *(const half8*)&Bs[(ni*16 + frow)*LDT + kq];
        #pragma unroll
        for (int mi = 0; mi < 2; ++mi)
            #pragma unroll
            for (int ni = 0; ni < 4; ++ni)
                acc[mi][ni] = __builtin_amdgcn_mfma_f32_16x16x32_f16(af[mi], bf[ni], acc[mi][ni], 0, 0, 0);
    }

    int col   = lane & 15;
    int rbase = (lane >> 4) * 4;
    #pragma unroll
    for (int mi = 0; mi < 2; ++mi) {
        #pragma unroll
        for (int ni = 0; ni < 4; ++ni) {
            #pragma unroll
            for (int r = 0; r < 4; ++r) {
                int row = m0 + wave*32 + mi*16 + rbase + r;
                int c   = n0 + ni*16 + col;
                float v = acc[mi][ni][r];
                if (skip) v += skip[(size_t)row*N + c];
                C[(size_t)row*N + c] = v;
            }
        }
    }
}

// ---------------- RoPE on q (sel=0, with 1/8 scale) and k (sel=1), fp32 ----------------
__global__ void rope_kernel(const float* __restrict__ pos,
                            const float* __restrict__ qkv,
                            float* __restrict__ qr) {
    int pix = blockIdx.x;
    int sel = blockIdx.y;   // 0=q, 1=k
    int t = threadIdx.x;    // 256: head = t/64, e = t%64
    int hw = pix % (HH*WW);
    const float* src = qkv + (size_t)pix*768 + sel*DM;
    float* dst = qr + (size_t)pix*512 + sel*DM;
    int e = t & 63;
    float v = src[t];
    float outv;
    if (e < 32) {
        int m = e & 15;
        int mf = m & 7;
        float p = (m < 8) ? pos[hw*2] : pos[hw*2 + 1];
        float freq = expf(1.14472988585f + mf * 0.287823136624f);
        float ang = p * freq;
        float c = cosf(ang), s = sinf(ang);
        float partner = (e < 16) ? src[t+16] : src[t-16];
        outv = (e < 16) ? fmaf(v, c, -partner*s) : fmaf(v, c, partner*s);
    } else {
        outv = v;
    }
    if (sel == 0) outv *= 0.125f;   // q / sqrt(64)
    dst[t] = outv;
}

// ---------------- neighborhood attention: one wave per query; fp16 output ----------------
__global__ __launch_bounds__(256) void attn_kernel(const float* __restrict__ qr,
                                                   const float* __restrict__ qkv,
                                                   _Float16* __restrict__ obuf) {
    int t = threadIdx.x;
    int wave = t >> 6, lane = t & 63;
    int qid = blockIdx.x * 4 + wave;        // ((b*NH+head)*H + h)*W + w
    int w = qid % WW; int tmp = qid / WW;
    int h = tmp % HH; tmp /= HH;
    int head = tmp % NH; int b = tmp / NH;
    int pix = (b*HH + h)*WW + w;

    __shared__ float q_sh[4][EH];
    __shared__ float a_sh[4][EH];

    q_sh[wave][lane] = qr[(size_t)pix*512 + head*EH + lane];
    __syncthreads();

    int sh = min(max(h-3, 0), HH-KS);
    int sw = min(max(w-3, 0), WW-KS);

    float dot = -3.0e38f;
    if (lane < 49) {
        int p = lane / 7, qq = lane % 7;
        const float* kp = qr + (size_t)((b*HH + sh+p)*WW + sw+qq)*512 + DM + head*EH;
        float acc = 0.f;
        #pragma unroll
        for (int e4 = 0; e4 < 16; ++e4) {
            float4 kv = *(const float4*)(kp + e4*4);
            acc = fmaf(q_sh[wave][e4*4+0], kv.x, acc);
            acc = fmaf(q_sh[wave][e4*4+1], kv.y, acc);
            acc = fmaf(q_sh[wave][e4*4+2], kv.z, acc);
            acc = fmaf(q_sh[wave][e4*4+3], kv.w, acc);
        }
        dot = acc;
    }
    float mx = dot;
    #pragma unroll
    for (int off = 32; off > 0; off >>= 1) mx = fmaxf(mx, __shfl_xor(mx, off, 64));
    float ex = (lane < 49) ? expf(dot - mx) : 0.f;
    float sm = ex;
    #pragma unroll
    for (int off = 32; off > 0; off >>= 1) sm += __shfl_xor(sm, off, 64);
    a_sh[wave][lane] = ex / sm;
    __syncthreads();

    float o = 0.f;
    #pragma unroll
    for (int j = 0; j < 49; ++j) {
        int p = j / 7, qq = j % 7;
        const float* vp = qkv + (size_t)((b*HH + sh+p)*WW + sw+qq)*768 + 2*DM + head*EH;
        o = fmaf(a_sh[wave][j], vp[lane], o);
    }
    obuf[(size_t)pix*DM + head*EH + lane] = (_Float16)o;  // (b,h,w,head,e)
}

extern "C" void kernel_launch(void* const* d_in, const int* in_sizes, int n_in,
                              void* d_out, int out_size, void* d_ws, size_t ws_size,
                              hipStream_t stream) {
    const float* x      = (const float*)d_in[0];
    const float* pos    = (const float*)d_in[1];
    const float* cond   = (const float*)d_in[2];
    const float* w_norm = (const float*)d_in[3];
    const float* w_qkv  = (const float*)d_in[4];
    const float* w_out  = (const float*)d_in[5];
    float* out = (float*)d_out;
    char* base = (char*)d_ws;

    // workspace layout (bytes, 256-aligned)
    float*    scale   = (float*)(base);                      // 512 f
    float*    qkv     = (float*)(base + 4096);               // NPIX*768 f = 14155776 B
    float*    qr      = (float*)(base + 4096 + 14155776);    // NPIX*512 f = 9437184 B
    _Float16* xn_h    = (_Float16*)(base + 4096 + 14155776 + 9437184);             // NPIX*256 h = 2359296 B
    _Float16* obuf_h  = (_Float16*)(base + 4096 + 14155776 + 9437184 + 2359296);   // NPIX*256 h
    _Float16* wqkv_h  = (_Float16*)(base + 4096 + 14155776 + 9437184 + 2*2359296); // 196608 h = 393216 B
    _Float16* wout_h  = (_Float16*)(base + 4096 + 14155776 + 9437184 + 2*2359296 + 393216); // 65536 h

    scale_kernel<<<dim3(N_B), dim3(DM), 0, stream>>>(cond, w_norm, scale);
    rmsnorm_kernel<<<dim3(NPIX), dim3(DM), 0, stream>>>(x, scale, xn_h);
    cast_f16_kernel<<<dim3(768), dim3(256), 0, stream>>>(w_qkv, wqkv_h, 768*DM);
    cast_f16_kernel<<<dim3(256), dim3(256), 0, stream>>>(w_out, wout_h, DM*DM);
    gemm_nt_f16<<<dim3(NPIX/128, 768/64), 256, 0, stream>>>(xn_h, wqkv_h, qkv, nullptr, NPIX, 768, DM);
    rope_kernel<<<dim3(NPIX, 2), dim3(DM), 0, stream>>>(pos, qkv, qr);
    attn_kernel<<<dim3(NQ/4), 256, 0, stream>>>(qr, qkv, obuf_h);
    gemm_nt_f16<<<dim3(NPIX/128, DM/64), 256, 0, stream>>>(obuf_h, wout_h, out, x, NPIX, DM, DM);
}

// Round 4
// 122.710 us; speedup vs baseline: 1.4434x; 1.4137x over previous
//
#include <hip/hip_runtime.h>
#include <math.h>

#define N_B 2
#define HH 48
#define WW 48
#define DM 256
#define NH 4
#define EH 64
#define KS 7
#define NPIX (N_B*HH*WW)    // 4608
#define NQ   (N_B*NH*HH*WW) // 18432 attention queries

typedef _Float16 half8 __attribute__((ext_vector_type(8)));
typedef float float4v __attribute__((ext_vector_type(4)));

// ---------------- scale = cond @ w_norm.T + 1 ----------------
__global__ void scale_kernel(const float* __restrict__ cond,
                             const float* __restrict__ w_norm,
                             float* __restrict__ scale) {
    int b = blockIdx.x, d = threadIdx.x;
    __shared__ float csh[DM];
    csh[d] = cond[b*DM + d];
    __syncthreads();
    const float* wr = w_norm + (size_t)d*DM;
    float acc = 0.f;
    #pragma unroll 8
    for (int c = 0; c < DM; ++c) acc += csh[c]*wr[c];
    scale[b*DM + d] = acc + 1.0f;
}

// ---------------- RMSNorm -> fp16 output ----------------
__global__ void rmsnorm_kernel(const float* __restrict__ x,
                               const float* __restrict__ scale,
                               _Float16* __restrict__ xn) {
    int pix = blockIdx.x, t = threadIdx.x;
    int b = pix / (HH*WW);
    float v = x[(size_t)pix*DM + t];
    float ss = v*v;
    #pragma unroll
    for (int off = 32; off > 0; off >>= 1) ss += __shfl_xor(ss, off, 64);
    __shared__ float wsum[4];
    if ((t & 63) == 0) wsum[t>>6] = ss;
    __syncthreads();
    float tot = wsum[0]+wsum[1]+wsum[2]+wsum[3];
    float r = rsqrtf(tot*(1.0f/DM) + 1e-6f);
    xn[(size_t)pix*DM + t] = (_Float16)(v * scale[b*DM + t] * r);
}

// ---------------- fp32 -> fp16 cast ----------------
__global__ void cast_f16_kernel(const float* __restrict__ src, _Float16* __restrict__ dst, int n) {
    int i = blockIdx.x*256 + threadIdx.x;
    if (i < n) dst[i] = (_Float16)src[i];
}

// ---------------- QKV GEMM (fp16 MFMA) + fused RoPE epilogue ----------------
// C = xn(4608x256) @ w_qkv^T(768x256); n-tile of 64 == one (sel, head).
// sel 0 (q): rope + 0.125 scale -> qh ; sel 1 (k): rope -> kh ; sel 2 (v): -> vh. All fp16 [pix][head*64+e].
__global__ __launch_bounds__(256) void gemm_qkv_f16(const _Float16* __restrict__ A,
                                                    const _Float16* __restrict__ B,
                                                    const float* __restrict__ pos,
                                                    _Float16* __restrict__ qh,
                                                    _Float16* __restrict__ kh,
                                                    _Float16* __restrict__ vh) {
    const int K = DM;
    const int LDT = 40;
    __shared__ _Float16 As[128*LDT];
    __shared__ _Float16 Bs[64*LDT];
    int t = threadIdx.x;
    int wave = t >> 6, lane = t & 63;
    int m0 = blockIdx.x*128, n0 = blockIdx.y*64;

    int lr = t >> 2;
    int lk = (t & 3) * 8;

    float4v acc[2][4];
    #pragma unroll
    for (int mi = 0; mi < 2; ++mi)
        #pragma unroll
        for (int ni = 0; ni < 4; ++ni)
            acc[mi][ni] = (float4v){0.f,0.f,0.f,0.f};

    int frow = lane & 15;
    int kq   = (lane >> 4) * 8;

    for (int k0 = 0; k0 < K; k0 += 32) {
        half8 a0 = *(const half8*)(A + (size_t)(m0 + lr)*K      + k0 + lk);
        half8 a1 = *(const half8*)(A + (size_t)(m0 + 64 + lr)*K + k0 + lk);
        half8 b0 = *(const half8*)(B + (size_t)(n0 + lr)*K      + k0 + lk);
        __syncthreads();
        *(half8*)&As[lr*LDT + lk]      = a0;
        *(half8*)&As[(64+lr)*LDT + lk] = a1;
        *(half8*)&Bs[lr*LDT + lk]      = b0;
        __syncthreads();
        half8 af[2], bf[4];
        af[0] = *(const half8*)&As[(wave*32 + frow)*LDT + kq];
        af[1] = *(const half8*)&As[(wave*32 + 16 + frow)*LDT + kq];
        #pragma unroll
        for (int ni = 0; ni < 4; ++ni)
            bf[ni] = *(const half8*)&Bs[(ni*16 + frow)*LDT + kq];
        #pragma unroll
        for (int mi = 0; mi < 2; ++mi)
            #pragma unroll
            for (int ni = 0; ni < 4; ++ni)
                acc[mi][ni] = __builtin_amdgcn_mfma_f32_16x16x32_f16(af[mi], bf[ni], acc[mi][ni], 0, 0, 0);
    }

    // Epilogue: e = ni*16 + col within this (sel, head); rope pairs (e, e+16) = (ni=0, ni=1), same lane.
    int sel  = n0 >> 8;
    int head = (n0 >> 6) & 3;
    _Float16* outp = (sel == 0) ? qh : (sel == 1) ? kh : vh;
    int col   = lane & 15;
    int rbase = (lane >> 4) * 4;
    float freq = __expf(1.14472988585f + (float)(col & 7) * 0.287823136624f); // pi * 10^(mf/8)
    #pragma unroll
    for (int mi = 0; mi < 2; ++mi) {
        #pragma unroll
        for (int r = 0; r < 4; ++r) {
            int pix = m0 + wave*32 + mi*16 + rbase + r;
            float v0 = acc[mi][0][r], v1 = acc[mi][1][r];
            float v2 = acc[mi][2][r], v3 = acc[mi][3][r];
            if (sel < 2) {
                int hw = pix % (HH*WW);
                float p = (col < 8) ? pos[hw*2] : pos[hw*2+1];
                float sn, cs;
                __sincosf(p*freq, &sn, &cs);
                float o0 = v0*cs - v1*sn;   // e < 16
                float o1 = v1*cs + v0*sn;   // 16 <= e < 32
                v0 = o0; v1 = o1;
                if (sel == 0) { v0*=0.125f; v1*=0.125f; v2*=0.125f; v3*=0.125f; }
            }
            size_t base = (size_t)pix*DM + head*EH;
            outp[base +  0 + col] = (_Float16)v0;
            outp[base + 16 + col] = (_Float16)v1;
            outp[base + 32 + col] = (_Float16)v2;
            outp[base + 48 + col] = (_Float16)v3;
        }
    }
}

// ---------------- MFMA neighborhood attention ----------------
// Block = 8x8 query tile for one (b, head). nb-space: 14 region rows x 16 cols (cols>=14 masked).
// S-phase fragments straight from global (dim axis contiguous & aligned); V^T + P staged in LDS.
__global__ __launch_bounds__(256) void attn_mfma(const _Float16* __restrict__ qg,
                                                 const _Float16* __restrict__ kg,
                                                 const _Float16* __restrict__ vg,
                                                 _Float16* __restrict__ obuf) {
    __shared__ _Float16 VT[64*232];   // [d][nb], rows 464B (16B-aligned, 8 bank-starts = b128 floor)
    __shared__ _Float16 SP[64*232];   // [q][nb], P in fp16
    int t = threadIdx.x;
    int wave = t >> 6, lane = t & 63;
    int col = lane & 15, quad = lane >> 4;
    int ty = blockIdx.x / 6, tx = blockIdx.x % 6;
    int b = blockIdx.y >> 2, head = blockIdx.y & 3;
    int qh0 = ty*8, qw0 = tx*8;
    int rh0 = min(max(qh0-3, 0), HH-14);
    int rw0 = min(max(qw0-3, 0), WW-14);

    // ---- stage V^T
    {
        int nbl = t & 31;
        int e0  = (t >> 5) * 8;
        #pragma unroll
        for (int pass = 0; pass < 7; ++pass) {
            int nb = pass*32 + nbl;
            int nr = nb >> 4, nc = nb & 15;
            int pix = (b*HH + rh0+nr)*WW + rw0 + nc;
            half8 vv = *(const half8*)(vg + (size_t)pix*DM + head*EH + e0);
            #pragma unroll
            for (int i = 0; i < 8; ++i)
                VT[(e0+i)*232 + nb] = vv[i];
        }
    }

    // ---- Q A-fragments (2 k-steps), direct from global
    int qidx_a = wave*16 + col;
    int pixq = (b*HH + qh0 + (qidx_a>>3))*WW + qw0 + (qidx_a & 7);
    const _Float16* qp = qg + (size_t)pixq*DM + head*EH;
    half8 qf0 = *(const half8*)(qp + quad*8);
    half8 qf1 = *(const half8*)(qp + 32 + quad*8);

    // ---- S = Q K^T : 14 n-tiles (one per region row), K frags direct from global
    float4v s[14];
    #pragma unroll
    for (int nr = 0; nr < 14; ++nr) {
        int pixk = (b*HH + rh0+nr)*WW + rw0 + col;
        const _Float16* kp = kg + (size_t)pixk*DM + head*EH;
        half8 kf0 = *(const half8*)(kp + quad*8);
        half8 kf1 = *(const half8*)(kp + 32 + quad*8);
        float4v a = (float4v){0.f,0.f,0.f,0.f};
        a = __builtin_amdgcn_mfma_f32_16x16x32_f16(qf0, kf0, a, 0, 0, 0);
        a = __builtin_amdgcn_mfma_f32_16x16x32_f16(qf1, kf1, a, 0, 0, 0);
        s[nr] = a;
    }

    // ---- mask + softmax in registers (row q = wave*16 + quad*4 + r lives in 16-lane col group)
    int sh_[4], uw_[4];
    #pragma unroll
    for (int r = 0; r < 4; ++r) {
        int qidx = wave*16 + quad*4 + r;
        int qhh = qh0 + (qidx>>3), qww = qw0 + (qidx & 7);
        sh_[r] = min(max(qhh-3, 0), HH-KS);
        int sw_ = min(max(qww-3, 0), WW-KS);
        uw_[r] = rw0 + col - sw_;           // valid iff 0 <= uw < 7
    }
    #pragma unroll
    for (int nr = 0; nr < 14; ++nr)
        #pragma unroll
        for (int r = 0; r < 4; ++r) {
            int uh = rh0 + nr - sh_[r];
            bool ok = ((unsigned)uh < 7u) && ((unsigned)uw_[r] < 7u);
            s[nr][r] = ok ? s[nr][r] : -1e30f;
        }
    #pragma unroll
    for (int r = 0; r < 4; ++r) {
        float m = s[0][r];
        #pragma unroll
        for (int nr = 1; nr < 14; ++nr) m = fmaxf(m, s[nr][r]);
        m = fmaxf(m, __shfl_xor(m, 1, 64));
        m = fmaxf(m, __shfl_xor(m, 2, 64));
        m = fmaxf(m, __shfl_xor(m, 4, 64));
        m = fmaxf(m, __shfl_xor(m, 8, 64));
        float sum = 0.f;
        #pragma unroll
        for (int nr = 0; nr < 14; ++nr) { float p = __expf(s[nr][r] - m); s[nr][r] = p; sum += p; }
        sum += __shfl_xor(sum, 1, 64);
        sum += __shfl_xor(sum, 2, 64);
        sum += __shfl_xor(sum, 4, 64);
        sum += __shfl_xor(sum, 8, 64);
        float rs = 1.f / sum;
        #pragma unroll
        for (int nr = 0; nr < 14; ++nr)
            SP[(wave*16 + quad*4 + r)*232 + nr*16 + col] = (_Float16)(s[nr][r] * rs);
    }
    __syncthreads();

    // ---- O = P V : A-frag from SP, B-frag from VT (both aligned b128)
    float4v o[4];
    #pragma unroll
    for (int dt = 0; dt < 4; ++dt) o[dt] = (float4v){0.f,0.f,0.f,0.f};
    #pragma unroll
    for (int ks = 0; ks < 7; ++ks) {
        half8 pa = *(const half8*)&SP[(wave*16 + col)*232 + ks*32 + quad*8];
        #pragma unroll
        for (int dt = 0; dt < 4; ++dt) {
            half8 vf = *(const half8*)&VT[(dt*16 + col)*232 + ks*32 + quad*8];
            o[dt] = __builtin_amdgcn_mfma_f32_16x16x32_f16(pa, vf, o[dt], 0, 0, 0);
        }
    }
    #pragma unroll
    for (int r = 0; r < 4; ++r) {
        int qidx = wave*16 + quad*4 + r;
        int pix = (b*HH + qh0 + (qidx>>3))*WW + qw0 + (qidx & 7);
        #pragma unroll
        for (int dt = 0; dt < 4; ++dt)
            obuf[(size_t)pix*DM + head*EH + dt*16 + col] = (_Float16)o[dt][r];
    }
}

// ---------------- out GEMM: C = obuf(4608x256) @ w_out^T + skip ----------------
__global__ __launch_bounds__(256) void gemm_nt_f16(const _Float16* __restrict__ A,
                                                   const _Float16* __restrict__ B,
                                                   float* __restrict__ C,
                                                   const float* __restrict__ skip,
                                                   int M, int N, int K) {
    const int LDT = 40;
    __shared__ _Float16 As[128*LDT];
    __shared__ _Float16 Bs[64*LDT];
    int t = threadIdx.x;
    int wave = t >> 6, lane = t & 63;
    int m0 = blockIdx.x*128, n0 = blockIdx.y*64;

    int lr = t >> 2;
    int lk = (t & 3) * 8;

    float4v acc[2][4];
    #pragma unroll
    for (int mi = 0; mi < 2; ++mi)
        #pragma unroll
        for (int ni = 0; ni < 4; ++ni)
            acc[mi][ni] = (float4v){0.f,0.f,0.f,0.f};

    int frow = lane & 15;
    int kq   = (lane >> 4) * 8;

    for (int k0 = 0; k0 < K; k0 += 32) {
        half8 a0 = *(const half8*)(A + (size_t)(m0 + lr)*K      + k0 + lk);
        half8 a1 = *(const half8*)(A + (size_t)(m0 + 64 + lr)*K + k0 + lk);
        half8 b0 = *(const half8*)(B + (size_t)(n0 + lr)*K      + k0 + lk);
        __syncthreads();
        *(half8*)&As[lr*LDT + lk]      = a0;
        *(half8*)&As[(64+lr)*LDT + lk] = a1;
        *(half8*)&Bs[lr*LDT + lk]      = b0;
        __syncthreads();
        half8 af[2], bf[4];
        af[0] = *(const half8*)&As[(wave*32 + frow)*LDT + kq];
        af[1] = *(const half8*)&As[(wave*32 + 16 + frow)*LDT + kq];
        #pragma unroll
        for (int ni = 0; ni < 4; ++ni)
            bf[ni] = *(const half8*)&Bs[(ni*16 + frow)*LDT + kq];
        #pragma unroll
        for (int mi = 0; mi < 2; ++mi)
            #pragma unroll
            for (int ni = 0; ni < 4; ++ni)
                acc[mi][ni] = __builtin_amdgcn_mfma_f32_16x16x32_f16(af[mi], bf[ni], acc[mi][ni], 0, 0, 0);
    }

    int col   = lane & 15;
    int rbase = (lane >> 4) * 4;
    #pragma unroll
    for (int mi = 0; mi < 2; ++mi) {
        #pragma unroll
        for (int ni = 0; ni < 4; ++ni) {
            #pragma unroll
            for (int r = 0; r < 4; ++r) {
                int row = m0 + wave*32 + mi*16 + rbase + r;
                int c   = n0 + ni*16 + col;
                float v = acc[mi][ni][r];
                if (skip) v += skip[(size_t)row*N + c];
                C[(size_t)row*N + c] = v;
            }
        }
    }
}

extern "C" void kernel_launch(void* const* d_in, const int* in_sizes, int n_in,
                              void* d_out, int out_size, void* d_ws, size_t ws_size,
                              hipStream_t stream) {
    const float* x      = (const float*)d_in[0];
    const float* pos    = (const float*)d_in[1];
    const float* cond   = (const float*)d_in[2];
    const float* w_norm = (const float*)d_in[3];
    const float* w_qkv  = (const float*)d_in[4];
    const float* w_out  = (const float*)d_in[5];
    float* out = (float*)d_out;
    char* base = (char*)d_ws;

    const size_t SZH = (size_t)NPIX*DM*2;   // fp16 [pix][256] buffer: 2,359,296 B
    const size_t PAD = 4096;                // overflow pad (attn edge reads run <=2 rows past)
    float*    scale  = (float*)(base);
    _Float16* xn_h   = (_Float16*)(base + PAD);
    _Float16* qh     = (_Float16*)(base + PAD + 1*(SZH+PAD));
    _Float16* kh     = (_Float16*)(base + PAD + 2*(SZH+PAD));
    _Float16* vh     = (_Float16*)(base + PAD + 3*(SZH+PAD));
    _Float16* obuf_h = (_Float16*)(base + PAD + 4*(SZH+PAD));
    _Float16* wqkv_h = (_Float16*)(base + PAD + 5*(SZH+PAD));
    _Float16* wout_h = (_Float16*)(base + PAD + 5*(SZH+PAD) + 786432);

    scale_kernel<<<dim3(N_B), dim3(DM), 0, stream>>>(cond, w_norm, scale);
    rmsnorm_kernel<<<dim3(NPIX), dim3(DM), 0, stream>>>(x, scale, xn_h);
    cast_f16_kernel<<<dim3(768), dim3(256), 0, stream>>>(w_qkv, wqkv_h, 768*DM);
    cast_f16_kernel<<<dim3(256), dim3(256), 0, stream>>>(w_out, wout_h, DM*DM);
    gemm_qkv_f16<<<dim3(NPIX/128, 12), 256, 0, stream>>>(xn_h, wqkv_h, pos, qh, kh, vh);
    attn_mfma<<<dim3(36, N_B*NH), 256, 0, stream>>>(qh, kh, vh, obuf_h);
    gemm_nt_f16<<<dim3(NPIX/128, DM/64), 256, 0, stream>>>(obuf_h, wout_h, out, x, NPIX, DM, DM);
}

// Round 5
// 105.779 us; speedup vs baseline: 1.6744x; 1.1601x over previous
//
#include <hip/hip_runtime.h>
#include <math.h>

#define N_B 2
#define HH 48
#define WW 48
#define DM 256
#define NH 4
#define EH 64
#define KS 7
#define NPIX (N_B*HH*WW)    // 4608

typedef _Float16 half8 __attribute__((ext_vector_type(8)));
typedef float float4v __attribute__((ext_vector_type(4)));

// ---------------- scale = cond @ w_norm.T + 1 ----------------
// grid (2,8) x 256: 8 lanes per output, float4 loads, shuffle reduce.
__global__ void scale_kernel(const float* __restrict__ cond,
                             const float* __restrict__ w_norm,
                             float* __restrict__ scale) {
    int b = blockIdx.x;
    int t = threadIdx.x, wave = t >> 6, lane = t & 63;
    int d = blockIdx.y*32 + wave*8 + (lane >> 3);
    int l8 = lane & 7;
    const float4* wr4 = (const float4*)(w_norm + (size_t)d*DM) + l8*8;
    const float4* c4  = (const float4*)(cond + (size_t)b*DM) + l8*8;
    float acc = 0.f;
    #pragma unroll
    for (int j = 0; j < 8; ++j) {
        float4 w = wr4[j], c = c4[j];
        acc += w.x*c.x + w.y*c.y + w.z*c.z + w.w*c.w;
    }
    acc += __shfl_xor(acc, 1, 64);
    acc += __shfl_xor(acc, 2, 64);
    acc += __shfl_xor(acc, 4, 64);
    if (l8 == 0) scale[b*DM + d] = acc + 1.0f;
}

// ---------------- RMSNorm -> fp16 output ----------------
__global__ void rmsnorm_kernel(const float* __restrict__ x,
                               const float* __restrict__ scale,
                               _Float16* __restrict__ xn) {
    int pix = blockIdx.x, t = threadIdx.x;
    int b = pix / (HH*WW);
    float v = x[(size_t)pix*DM + t];
    float ss = v*v;
    #pragma unroll
    for (int off = 32; off > 0; off >>= 1) ss += __shfl_xor(ss, off, 64);
    __shared__ float wsum[4];
    if ((t & 63) == 0) wsum[t>>6] = ss;
    __syncthreads();
    float tot = wsum[0]+wsum[1]+wsum[2]+wsum[3];
    float r = rsqrtf(tot*(1.0f/DM) + 1e-6f);
    xn[(size_t)pix*DM + t] = (_Float16)(v * scale[b*DM + t] * r);
}

// ---------------- QKV GEMM (fp16 MFMA, fp32 B cast in staging) + fused RoPE ----------------
// 64x64 tile, 4 waves x (16x64), BK=32. n-tile of 64 == one (sel, head).
__global__ __launch_bounds__(256) void gemm_qkv_f16(const _Float16* __restrict__ A,
                                                    const float* __restrict__ B,
                                                    const float* __restrict__ pos,
                                                    _Float16* __restrict__ qh,
                                                    _Float16* __restrict__ kh,
                                                    _Float16* __restrict__ vh) {
    const int K = DM, LDT = 40;
    __shared__ _Float16 As[64*LDT];
    __shared__ _Float16 Bs[64*LDT];
    int t = threadIdx.x;
    int wave = t >> 6, lane = t & 63;
    int m0 = blockIdx.x*64, n0 = blockIdx.y*64;
    int lr = t >> 2, lk = (t & 3) * 8;

    float4v acc[4];
    #pragma unroll
    for (int ni = 0; ni < 4; ++ni) acc[ni] = (float4v){0.f,0.f,0.f,0.f};

    int frow = lane & 15, kq = (lane >> 4) * 8;

    for (int k0 = 0; k0 < K; k0 += 32) {
        half8 a0 = *(const half8*)(A + (size_t)(m0 + lr)*K + k0 + lk);
        const float* bp = B + (size_t)(n0 + lr)*K + k0 + lk;
        float4 b0 = *(const float4*)bp;
        float4 b1 = *(const float4*)(bp + 4);
        half8 hb;
        hb[0]=(_Float16)b0.x; hb[1]=(_Float16)b0.y; hb[2]=(_Float16)b0.z; hb[3]=(_Float16)b0.w;
        hb[4]=(_Float16)b1.x; hb[5]=(_Float16)b1.y; hb[6]=(_Float16)b1.z; hb[7]=(_Float16)b1.w;
        __syncthreads();
        *(half8*)&As[lr*LDT + lk] = a0;
        *(half8*)&Bs[lr*LDT + lk] = hb;
        __syncthreads();
        half8 af = *(const half8*)&As[(wave*16 + frow)*LDT + kq];
        #pragma unroll
        for (int ni = 0; ni < 4; ++ni) {
            half8 bf = *(const half8*)&Bs[(ni*16 + frow)*LDT + kq];
            acc[ni] = __builtin_amdgcn_mfma_f32_16x16x32_f16(af, bf, acc[ni], 0, 0, 0);
        }
    }

    // Epilogue: e = ni*16 + col; rope pairs (e, e+16) = (ni=0, ni=1), same lane.
    int sel  = n0 >> 8;
    int head = (n0 >> 6) & 3;
    _Float16* outp = (sel == 0) ? qh : (sel == 1) ? kh : vh;
    int col = lane & 15, rbase = (lane >> 4) * 4;
    float freq = __expf(1.14472988585f + (float)(col & 7) * 0.287823136624f); // pi * 10^(mf/8)
    #pragma unroll
    for (int r = 0; r < 4; ++r) {
        int pix = m0 + wave*16 + rbase + r;
        float v0 = acc[0][r], v1 = acc[1][r], v2 = acc[2][r], v3 = acc[3][r];
        if (sel < 2) {
            int hw = pix % (HH*WW);
            float p = (col < 8) ? pos[hw*2] : pos[hw*2+1];
            float sn, cs;
            __sincosf(p*freq, &sn, &cs);
            float o0 = v0*cs - v1*sn;
            float o1 = v1*cs + v0*sn;
            v0 = o0; v1 = o1;
            if (sel == 0) { v0*=0.125f; v1*=0.125f; v2*=0.125f; v3*=0.125f; }
        }
        size_t base = (size_t)pix*DM + head*EH;
        outp[base +  0 + col] = (_Float16)v0;
        outp[base + 16 + col] = (_Float16)v1;
        outp[base + 32 + col] = (_Float16)v2;
        outp[base + 48 + col] = (_Float16)v3;
    }
}

// ---------------- MFMA neighborhood attention (unchanged from R4) ----------------
__global__ __launch_bounds__(256) void attn_mfma(const _Float16* __restrict__ qg,
                                                 const _Float16* __restrict__ kg,
                                                 const _Float16* __restrict__ vg,
                                                 _Float16* __restrict__ obuf) {
    __shared__ _Float16 VT[64*232];   // [d][nb]
    __shared__ _Float16 SP[64*232];   // [q][nb]
    int t = threadIdx.x;
    int wave = t >> 6, lane = t & 63;
    int col = lane & 15, quad = lane >> 4;
    int ty = blockIdx.x / 6, tx = blockIdx.x % 6;
    int b = blockIdx.y >> 2, head = blockIdx.y & 3;
    int qh0 = ty*8, qw0 = tx*8;
    int rh0 = min(max(qh0-3, 0), HH-14);
    int rw0 = min(max(qw0-3, 0), WW-14);

    {
        int nbl = t & 31;
        int e0  = (t >> 5) * 8;
        #pragma unroll
        for (int pass = 0; pass < 7; ++pass) {
            int nb = pass*32 + nbl;
            int nr = nb >> 4, nc = nb & 15;
            int pix = (b*HH + rh0+nr)*WW + rw0 + nc;
            half8 vv = *(const half8*)(vg + (size_t)pix*DM + head*EH + e0);
            #pragma unroll
            for (int i = 0; i < 8; ++i)
                VT[(e0+i)*232 + nb] = vv[i];
        }
    }

    int qidx_a = wave*16 + col;
    int pixq = (b*HH + qh0 + (qidx_a>>3))*WW + qw0 + (qidx_a & 7);
    const _Float16* qp = qg + (size_t)pixq*DM + head*EH;
    half8 qf0 = *(const half8*)(qp + quad*8);
    half8 qf1 = *(const half8*)(qp + 32 + quad*8);

    float4v s[14];
    #pragma unroll
    for (int nr = 0; nr < 14; ++nr) {
        int pixk = (b*HH + rh0+nr)*WW + rw0 + col;
        const _Float16* kp = kg + (size_t)pixk*DM + head*EH;
        half8 kf0 = *(const half8*)(kp + quad*8);
        half8 kf1 = *(const half8*)(kp + 32 + quad*8);
        float4v a = (float4v){0.f,0.f,0.f,0.f};
        a = __builtin_amdgcn_mfma_f32_16x16x32_f16(qf0, kf0, a, 0, 0, 0);
        a = __builtin_amdgcn_mfma_f32_16x16x32_f16(qf1, kf1, a, 0, 0, 0);
        s[nr] = a;
    }

    int sh_[4], uw_[4];
    #pragma unroll
    for (int r = 0; r < 4; ++r) {
        int qidx = wave*16 + quad*4 + r;
        int qhh = qh0 + (qidx>>3), qww = qw0 + (qidx & 7);
        sh_[r] = min(max(qhh-3, 0), HH-KS);
        int sw_ = min(max(qww-3, 0), WW-KS);
        uw_[r] = rw0 + col - sw_;
    }
    #pragma unroll
    for (int nr = 0; nr < 14; ++nr)
        #pragma unroll
        for (int r = 0; r < 4; ++r) {
            int uh = rh0 + nr - sh_[r];
            bool ok = ((unsigned)uh < 7u) && ((unsigned)uw_[r] < 7u);
            s[nr][r] = ok ? s[nr][r] : -1e30f;
        }
    #pragma unroll
    for (int r = 0; r < 4; ++r) {
        float m = s[0][r];
        #pragma unroll
        for (int nr = 1; nr < 14; ++nr) m = fmaxf(m, s[nr][r]);
        m = fmaxf(m, __shfl_xor(m, 1, 64));
        m = fmaxf(m, __shfl_xor(m, 2, 64));
        m = fmaxf(m, __shfl_xor(m, 4, 64));
        m = fmaxf(m, __shfl_xor(m, 8, 64));
        float sum = 0.f;
        #pragma unroll
        for (int nr = 0; nr < 14; ++nr) { float p = __expf(s[nr][r] - m); s[nr][r] = p; sum += p; }
        sum += __shfl_xor(sum, 1, 64);
        sum += __shfl_xor(sum, 2, 64);
        sum += __shfl_xor(sum, 4, 64);
        sum += __shfl_xor(sum, 8, 64);
        float rs = 1.f / sum;
        #pragma unroll
        for (int nr = 0; nr < 14; ++nr)
            SP[(wave*16 + quad*4 + r)*232 + nr*16 + col] = (_Float16)(s[nr][r] * rs);
    }
    __syncthreads();

    float4v o[4];
    #pragma unroll
    for (int dt = 0; dt < 4; ++dt) o[dt] = (float4v){0.f,0.f,0.f,0.f};
    #pragma unroll
    for (int ks = 0; ks < 7; ++ks) {
        half8 pa = *(const half8*)&SP[(wave*16 + col)*232 + ks*32 + quad*8];
        #pragma unroll
        for (int dt = 0; dt < 4; ++dt) {
            half8 vf = *(const half8*)&VT[(dt*16 + col)*232 + ks*32 + quad*8];
            o[dt] = __builtin_amdgcn_mfma_f32_16x16x32_f16(pa, vf, o[dt], 0, 0, 0);
        }
    }
    #pragma unroll
    for (int r = 0; r < 4; ++r) {
        int qidx = wave*16 + quad*4 + r;
        int pix = (b*HH + qh0 + (qidx>>3))*WW + qw0 + (qidx & 7);
        #pragma unroll
        for (int dt = 0; dt < 4; ++dt)
            obuf[(size_t)pix*DM + head*EH + dt*16 + col] = (_Float16)o[dt][r];
    }
}

// ---------------- out GEMM: C = obuf @ w_out^T + skip (fp32 B cast in staging) ----------------
__global__ __launch_bounds__(256) void gemm_out_f16(const _Float16* __restrict__ A,
                                                    const float* __restrict__ B,
                                                    float* __restrict__ C,
                                                    const float* __restrict__ skip) {
    const int K = DM, N = DM, LDT = 40;
    __shared__ _Float16 As[64*LDT];
    __shared__ _Float16 Bs[64*LDT];
    int t = threadIdx.x;
    int wave = t >> 6, lane = t & 63;
    int m0 = blockIdx.x*64, n0 = blockIdx.y*64;
    int lr = t >> 2, lk = (t & 3) * 8;

    float4v acc[4];
    #pragma unroll
    for (int ni = 0; ni < 4; ++ni) acc[ni] = (float4v){0.f,0.f,0.f,0.f};

    int frow = lane & 15, kq = (lane >> 4) * 8;

    for (int k0 = 0; k0 < K; k0 += 32) {
        half8 a0 = *(const half8*)(A + (size_t)(m0 + lr)*K + k0 + lk);
        const float* bp = B + (size_t)(n0 + lr)*K + k0 + lk;
        float4 b0 = *(const float4*)bp;
        float4 b1 = *(const float4*)(bp + 4);
        half8 hb;
        hb[0]=(_Float16)b0.x; hb[1]=(_Float16)b0.y; hb[2]=(_Float16)b0.z; hb[3]=(_Float16)b0.w;
        hb[4]=(_Float16)b1.x; hb[5]=(_Float16)b1.y; hb[6]=(_Float16)b1.z; hb[7]=(_Float16)b1.w;
        __syncthreads();
        *(half8*)&As[lr*LDT + lk] = a0;
        *(half8*)&Bs[lr*LDT + lk] = hb;
        __syncthreads();
        half8 af = *(const half8*)&As[(wave*16 + frow)*LDT + kq];
        #pragma unroll
        for (int ni = 0; ni < 4; ++ni) {
            half8 bf = *(const half8*)&Bs[(ni*16 + frow)*LDT + kq];
            acc[ni] = __builtin_amdgcn_mfma_f32_16x16x32_f16(af, bf, acc[ni], 0, 0, 0);
        }
    }

    int col = lane & 15, rbase = (lane >> 4) * 4;
    #pragma unroll
    for (int ni = 0; ni < 4; ++ni) {
        #pragma unroll
        for (int r = 0; r < 4; ++r) {
            int row = m0 + wave*16 + rbase + r;
            int c   = n0 + ni*16 + col;
            C[(size_t)row*N + c] = acc[ni][r] + skip[(size_t)row*N + c];
        }
    }
}

extern "C" void kernel_launch(void* const* d_in, const int* in_sizes, int n_in,
                              void* d_out, int out_size, void* d_ws, size_t ws_size,
                              hipStream_t stream) {
    const float* x      = (const float*)d_in[0];
    const float* pos    = (const float*)d_in[1];
    const float* cond   = (const float*)d_in[2];
    const float* w_norm = (const float*)d_in[3];
    const float* w_qkv  = (const float*)d_in[4];
    const float* w_out  = (const float*)d_in[5];
    float* out = (float*)d_out;
    char* base = (char*)d_ws;

    const size_t SZH = (size_t)NPIX*DM*2;   // fp16 [pix][256]: 2,359,296 B
    const size_t PAD = 4096;                // attn edge reads overrun <=2 pixels
    float*    scale  = (float*)(base);
    _Float16* xn_h   = (_Float16*)(base + PAD);
    _Float16* qh     = (_Float16*)(base + PAD + 1*(SZH+PAD));
    _Float16* kh     = (_Float16*)(base + PAD + 2*(SZH+PAD));
    _Float16* vh     = (_Float16*)(base + PAD + 3*(SZH+PAD));
    _Float16* obuf_h = (_Float16*)(base + PAD + 4*(SZH+PAD));

    scale_kernel<<<dim3(N_B, 8), 256, 0, stream>>>(cond, w_norm, scale);
    rmsnorm_kernel<<<dim3(NPIX), dim3(DM), 0, stream>>>(x, scale, xn_h);
    gemm_qkv_f16<<<dim3(NPIX/64, 12), 256, 0, stream>>>(xn_h, w_qkv, pos, qh, kh, vh);
    attn_mfma<<<dim3(36, N_B*NH), 256, 0, stream>>>(qh, kh, vh, obuf_h);
    gemm_out_f16<<<dim3(NPIX/64, DM/64), 256, 0, stream>>>(obuf_h, w_out, out, x);
}